// Round 5
// baseline (427.779 us; speedup 1.0000x reference)
//
#include <hip/hip_runtime.h>
#include <hip/hip_bf16.h>
#include <cstdint>

typedef __hip_bfloat16 bf16;
typedef __attribute__((ext_vector_type(8))) short short8;
typedef __attribute__((ext_vector_type(4))) float f32x4;

__device__ __forceinline__ float bf2f(bf16 v) { return __bfloat162float(v); }
__device__ __forceinline__ bf16  f2bf(float v) { return __float2bfloat16(v); }
__device__ __forceinline__ uint32_t pack2(float a, float b) {
  bf16 x = f2bf(a), y = f2bf(b);
  uint16_t xa = *(uint16_t*)&x, ya = *(uint16_t*)&y;
  return (uint32_t)xa | ((uint32_t)ya << 16);
}

// window-order row m -> token index (t*4096 + p)
__device__ __forceinline__ int win_to_token(int m) {
  int n = m >> 8, l = m & 255;
  int t = n >> 4, win = n & 15;
  int wi = win >> 2, wj = win & 3;
  int u = l >> 4, v = l & 15;
  return (t << 12) | ((wi * 16 + u) << 6) | (wj * 16 + v);
}

// ---------------- kernel 1: pool + selector MLP + gumbel mask ----------------
__global__ __launch_bounds__(64) void k_selector(
    const float* __restrict__ x, const float* __restrict__ gu,
    const float* __restrict__ s1w, const float* __restrict__ s1b,
    const float* __restrict__ s2w, const float* __restrict__ s2b,
    const float* __restrict__ s3w, const float* __restrict__ s3b,
    float* __restrict__ f1o, float* __restrict__ f2o, float* __restrict__ f3o,
    float* __restrict__ maskp) {
  int t = blockIdx.x, lane = threadIdx.x;
  int th = t >> 2, tw = t & 3;
  __shared__ float pooled[192];
  __shared__ float f1s[64], f2s[32], f3s[2];
  for (int o = lane; o < 192; o += 64) {
    int ch = o % 3, j = (o / 3) & 7, i = o / 24;
    const float* xp = x + ch * 65536 + (th * 64 + i * 8) * 256 + (tw * 64 + j * 8);
    float s = 0.f;
    for (int a = 0; a < 8; ++a)
      for (int b = 0; b < 8; ++b) s += xp[a * 256 + b];
    pooled[o] = s * (1.0f / 64.0f);
  }
  __syncthreads();
  {
    float s = s1b[lane];
    for (int k = 0; k < 192; ++k) s = fmaf(pooled[k], s1w[k * 64 + lane], s);
    f1o[t * 64 + lane] = s;
    f1s[lane] = fmaxf(s, 0.f);
  }
  __syncthreads();
  if (lane < 32) {
    float s = s2b[lane];
    for (int k = 0; k < 64; ++k) s = fmaf(f1s[k], s2w[k * 32 + lane], s);
    f2o[t * 32 + lane] = s;
    f2s[lane] = fmaxf(s, 0.f);
  }
  __syncthreads();
  if (lane < 2) {
    float s = s3b[lane];
    for (int k = 0; k < 32; ++k) s = fmaf(f2s[k], s3w[k * 2 + lane], s);
    f3o[t * 2 + lane] = s;
    f3s[lane] = s;
  }
  __syncthreads();
  if (lane == 0) {
    float g0 = -logf(-logf(gu[t * 2 + 0] + 1e-10f) + 1e-10f);
    float g1 = -logf(-logf(gu[t * 2 + 1] + 1e-10f) + 1e-10f);
    maskp[t] = (f3s[1] + g1 > f3s[0] + g0) ? 1.0f : 0.0f;
  }
}

// ---------------- pack all weights to bf16 Bt[n][k] (transposed, padded) ----------------
__global__ __launch_bounds__(256) void k_packB(
    const float* __restrict__ qkvw, const float* __restrict__ projw,
    const float* __restrict__ mlp1w, const float* __restrict__ mlp2w,
    const float* __restrict__ upw, bf16* __restrict__ Bt_qkv,
    bf16* __restrict__ Bt_proj, bf16* __restrict__ Bt_mlp1,
    bf16* __restrict__ Bt_mlp2, bf16* __restrict__ Bt_up) {
  int idx = blockIdx.x * 256 + threadIdx.x;
  const int e0 = 576 * 192, e1 = e0 + 192 * 192, e2 = e1 + 384 * 192,
            e3 = e2 + 192 * 384, e4 = e3 + 64 * 192;
  const float* src; bf16* dst; int K, N, KP, base;
  if (idx < e0)      { src = qkvw;  dst = Bt_qkv;  K = 180; N = 540; KP = 192; base = 0; }
  else if (idx < e1) { src = projw; dst = Bt_proj; K = 180; N = 180; KP = 192; base = e0; }
  else if (idx < e2) { src = mlp1w; dst = Bt_mlp1; K = 180; N = 360; KP = 192; base = e1; }
  else if (idx < e3) { src = mlp2w; dst = Bt_mlp2; K = 360; N = 180; KP = 384; base = e2; }
  else if (idx < e4) { src = upw;   dst = Bt_up;   K = 180; N = 48;  KP = 192; base = e3; }
  else return;
  int off = idx - base;
  int n = off / KP, k = off % KP;
  float v = (k < K && n < N) ? src[(size_t)k * N + n] : 0.f;
  dst[off] = f2bf(v);
}

// ---------------- embed (3->180) + LN1 applied, outputs window-major ----------------
__global__ __launch_bounds__(256) void k_embed(
    const float* __restrict__ x, const float* __restrict__ ew,
    const float* __restrict__ eb, const float* __restrict__ g1,
    const float* __restrict__ b1, bf16* __restrict__ tok,
    bf16* __restrict__ Aq) {
  int wrow = blockIdx.x * 4 + (threadIdx.x >> 6);
  int lane = threadIdx.x & 63;
  int token = win_to_token(wrow);
  int t = token >> 12, p = token & 4095;
  int r = p >> 6, c = p & 63;
  int gh = (t >> 2) * 64 + r, gw = (t & 3) * 64 + c;
  float x0 = x[gh * 256 + gw];
  float x1 = x[65536 + gh * 256 + gw];
  float x2 = x[131072 + gh * 256 + gw];
  float v[3];
  float s = 0.f, s2 = 0.f;
#pragma unroll
  for (int i = 0; i < 3; ++i) {
    int e = lane + i * 64;
    float vv = 0.f;
    if (e < 180) {
      vv = eb[e];
      vv = fmaf(x0, ew[e], vv);
      vv = fmaf(x1, ew[180 + e], vv);
      vv = fmaf(x2, ew[360 + e], vv);
      tok[(size_t)wrow * 180 + e] = f2bf(vv);
      s += vv; s2 = fmaf(vv, vv, s2);
    }
    v[i] = vv;
  }
#pragma unroll
  for (int off = 32; off; off >>= 1) { s += __shfl_xor(s, off); s2 += __shfl_xor(s2, off); }
  float mu = s * (1.f / 180.f);
  float rs = rsqrtf(s2 * (1.f / 180.f) - mu * mu + 1e-5f);
#pragma unroll
  for (int i = 0; i < 3; ++i) {
    int e = lane + i * 64;
    if (e < 192) {
      float a = (e < 180) ? ((v[i] - mu) * rs * g1[e] + b1[e]) : 0.f;
      Aq[(size_t)wrow * 192 + e] = f2bf(a);
    }
  }
}

// ---------------- LN2 prep ----------------
__global__ __launch_bounds__(256) void k_ln2prep(
    const bf16* __restrict__ tok, const float* __restrict__ g2,
    const float* __restrict__ b2, bf16* __restrict__ A2) {
  int wrow = blockIdx.x * 4 + (threadIdx.x >> 6);
  int lane = threadIdx.x & 63;
  float v[3];
  float s = 0.f, s2 = 0.f;
#pragma unroll
  for (int i = 0; i < 3; ++i) {
    int e = lane + i * 64;
    float vv = 0.f;
    if (e < 180) {
      vv = bf2f(tok[(size_t)wrow * 180 + e]);
      s += vv; s2 = fmaf(vv, vv, s2);
    }
    v[i] = vv;
  }
#pragma unroll
  for (int off = 32; off; off >>= 1) { s += __shfl_xor(s, off); s2 += __shfl_xor(s2, off); }
  float mu = s * (1.f / 180.f);
  float rs = rsqrtf(s2 * (1.f / 180.f) - mu * mu + 1e-5f);
#pragma unroll
  for (int i = 0; i < 3; ++i) {
    int e = lane + i * 64;
    if (e < 192) {
      float a = (e < 180) ? ((v[i] - mu) * rs * g2[e] + b2[e]) : 0.f;
      A2[(size_t)wrow * 192 + e] = f2bf(a);
    }
  }
}

// ---------------- zero head-pad cols (d=30,31) of Qp/Kp ----------------
__global__ __launch_bounds__(256) void k_padzero(bf16* __restrict__ Qp,
                                                 bf16* __restrict__ Kp) {
  int row = blockIdx.x * 256 + threadIdx.x;
#pragma unroll
  for (int hd = 0; hd < 6; ++hd) {
    *(uint32_t*)&Qp[(size_t)row * 192 + hd * 32 + 30] = 0;
    *(uint32_t*)&Kp[(size_t)row * 192 + hd * 32 + 30] = 0;
  }
}

// ---------------- MFMA GEMM, n-loop in-block: A-frags in registers, read once ----------
// EPI: 0=plain store, 1=accum into C, 2=gelu+pad store, 3=QKV split
// MT: M-tile (128 -> RF=2, 64 -> RF=1); wave w owns rows w*(MT/4) .. +MT/4-1
template <int KPAD, int MT, int EPI>
__global__ __launch_bounds__(256) void k_gemm_nloop(
    const bf16* __restrict__ A, int ldA,
    const bf16* __restrict__ Bt, const float* __restrict__ bias,
    bf16* __restrict__ Cp, int ldC, int N, int NT,
    bf16* __restrict__ Qo, bf16* __restrict__ Ko, bf16* __restrict__ Vo) {
  constexpr int RF = MT / 64;   // 16-row fragments per wave
  constexpr int KS = KPAD / 32; // K-steps
  const int tid = threadIdx.x;
  const int w = tid >> 6, l = tid & 63;
  const int lr = l & 15, lk = l >> 4;
  const int m0 = blockIdx.x * MT;
  // A-fragments: read each A element exactly once per block
  short8 fa[RF][KS];
  const bf16* Abase = A + (size_t)(m0 + w * (MT / 4) + lr) * ldA + lk * 8;
#pragma unroll
  for (int i = 0; i < RF; ++i)
#pragma unroll
    for (int ks = 0; ks < KS; ++ks)
      fa[i][ks] = *(const short8*)(Abase + (size_t)i * 16 * ldA + ks * 32);
  for (int nt = 0; nt < NT; ++nt) {
    const int n0 = nt * 64;
    const bf16* Brow = Bt + (size_t)(n0 + lr) * KPAD + lk * 8;
    f32x4 acc[RF][4];
#pragma unroll
    for (int i = 0; i < RF; ++i)
#pragma unroll
      for (int j = 0; j < 4; ++j) acc[i][j] = (f32x4){0.f, 0.f, 0.f, 0.f};
#pragma unroll
    for (int ks = 0; ks < KS; ++ks) {
      short8 fb[4];
#pragma unroll
      for (int j = 0; j < 4; ++j)
        fb[j] = *(const short8*)(Brow + (size_t)j * 16 * KPAD + ks * 32);
#pragma unroll
      for (int i = 0; i < RF; ++i)
#pragma unroll
        for (int j = 0; j < 4; ++j)
          acc[i][j] = __builtin_amdgcn_mfma_f32_16x16x32_bf16(fa[i][ks], fb[j], acc[i][j], 0, 0, 0);
    }
#pragma unroll
    for (int i = 0; i < RF; ++i) {
      int mbase = m0 + w * (MT / 4) + i * 16 + lk * 4;
#pragma unroll
      for (int j = 0; j < 4; ++j) {
        int n = n0 + j * 16 + lr;
#pragma unroll
        for (int q = 0; q < 4; ++q) {
          int m = mbase + q;
          if (n >= N) {
            if (EPI == 2 && n < ldC) Cp[(size_t)m * ldC + n] = f2bf(0.f);
            continue;
          }
          float vv = acc[i][j][q] + bias[n];
          if (EPI == 2) {
            float u = 0.7978845608028654f * (vv + 0.044715f * vv * vv * vv);
            vv = vv / (1.f + __expf(-2.f * u));
          }
          if (EPI == 3) {
            int buf = n / 180, dp = n % 180;
            int hd = dp / 30, dd = dp % 30;
            int colp = hd * 32 + dd;
            if (buf == 0)      Qo[(size_t)m * 192 + colp] = f2bf(vv);
            else if (buf == 1) Ko[(size_t)m * 192 + colp] = f2bf(vv);
            else               Vo[(size_t)colp * 65536 + m] = f2bf(vv);
          } else {
            bf16* cp = Cp + (size_t)m * ldC + n;
            if (EPI == 1) vv += bf2f(*cp);
            *cp = f2bf(vv);
          }
        }
      }
    }
  }
}

// ---------------- MFMA attention: block = (window, head), 4 waves ----------------
__global__ __launch_bounds__(256) void k_attn_mfma(
    const bf16* __restrict__ Qp, const bf16* __restrict__ Kp,
    const bf16* __restrict__ Vt, bf16* __restrict__ av) {
  const int blk = blockIdx.x;
  const int win = blk / 6, hd = blk % 6;
  const int tid = threadIdx.x;
  const int w = tid >> 6, l = tid & 63;
  const int lr = l & 15, lk = l >> 4;
  const float scale = 0.18257418583505536f;  // 1/sqrt(30)

  __shared__ bf16 Ks[256][40];
  __shared__ bf16 Vs[32][264];
  __shared__ bf16 Ps[4][16][264];

  {
    const bf16* src = Kp + (size_t)(win * 256 + tid) * 192 + hd * 32;
#pragma unroll
    for (int c = 0; c < 4; ++c)
      *(short8*)&Ks[tid][c * 8] = *(const short8*)(src + c * 8);
  }
  {
    int d = tid >> 3, ck = tid & 7;
    const bf16* src = Vt + (size_t)(hd * 32 + d) * 65536 + win * 256 + ck * 32;
#pragma unroll
    for (int c = 0; c < 4; ++c)
      *(short8*)&Vs[d][ck * 32 + c * 8] = *(const short8*)(src + c * 8);
  }
  __syncthreads();

  for (int qt = 0; qt < 4; ++qt) {
    const int qbase = qt * 64 + w * 16;
    short8 fq = *(const short8*)(Qp + (size_t)(win * 256 + qbase + lr) * 192 + hd * 32 + lk * 8);
    f32x4 accS[16];
#pragma unroll
    for (int kt = 0; kt < 16; ++kt) {
      short8 fk = *(const short8*)(&Ks[kt * 16 + lr][lk * 8]);
      accS[kt] = __builtin_amdgcn_mfma_f32_16x16x32_bf16(
          fk, fq, (f32x4){0.f, 0.f, 0.f, 0.f}, 0, 0, 0);
    }
    float mraw = -1e30f;
#pragma unroll
    for (int kt = 0; kt < 16; ++kt)
#pragma unroll
      for (int r = 0; r < 4; ++r) mraw = fmaxf(mraw, accS[kt][r]);
    mraw = fmaxf(mraw, __shfl_xor(mraw, 16));
    mraw = fmaxf(mraw, __shfl_xor(mraw, 32));
    const float mc = mraw * scale;
    float lsum = 0.f;
#pragma unroll
    for (int kt = 0; kt < 16; ++kt) {
      float p0 = __expf(fmaf(accS[kt][0], scale, -mc));
      float p1 = __expf(fmaf(accS[kt][1], scale, -mc));
      float p2 = __expf(fmaf(accS[kt][2], scale, -mc));
      float p3 = __expf(fmaf(accS[kt][3], scale, -mc));
      lsum += (p0 + p1) + (p2 + p3);
      uint32_t d0 = pack2(p0, p1), d1 = pack2(p2, p3);
      *(uint32_t*)&Ps[w][lr][kt * 16 + lk * 4]     = d0;
      *(uint32_t*)&Ps[w][lr][kt * 16 + lk * 4 + 2] = d1;
    }
    lsum += __shfl_xor(lsum, 16);
    lsum += __shfl_xor(lsum, 32);
    __syncthreads();
    f32x4 accO0 = (f32x4){0.f, 0.f, 0.f, 0.f};
    f32x4 accO1 = (f32x4){0.f, 0.f, 0.f, 0.f};
#pragma unroll
    for (int ks = 0; ks < 8; ++ks) {
      short8 fp = *(const short8*)(&Ps[w][lr][ks * 32 + lk * 8]);
      short8 fv0 = *(const short8*)(&Vs[lr][ks * 32 + lk * 8]);
      short8 fv1 = *(const short8*)(&Vs[16 + lr][ks * 32 + lk * 8]);
      accO0 = __builtin_amdgcn_mfma_f32_16x16x32_bf16(fp, fv0, accO0, 0, 0, 0);
      accO1 = __builtin_amdgcn_mfma_f32_16x16x32_bf16(fp, fv1, accO1, 0, 0, 0);
    }
    float invl = 1.f / lsum;
#pragma unroll
    for (int r = 0; r < 4; ++r) {
      float inv_r = __shfl(invl, lk * 4 + r);
      int row = win * 256 + qbase + lk * 4 + r;
      int d0 = lr, d1 = 16 + lr;
      if (d0 < 30) av[(size_t)row * 192 + hd * 30 + d0] = f2bf(accO0[r] * inv_r);
      if (d1 < 30) av[(size_t)row * 192 + hd * 30 + d1] = f2bf(accO1[r] * inv_r);
      if (hd == 0 && lr < 12) av[(size_t)row * 192 + 180 + lr] = f2bf(0.f);
    }
    __syncthreads();
  }
}

// ---------------- bicubic weights (jax Keys a=-0.5, half-pixel, edge renorm) ----------------
__device__ const float c_cubw[4][4] = {
    {-0.0439453125f, 0.3896484375f, 0.7275390625f, -0.0732421875f},
    {-0.0068359375f, 0.0908203125f, 0.9638671875f, -0.0478515625f},
    {-0.0478515625f, 0.9638671875f, 0.0908203125f, -0.0068359375f},
    {-0.0732421875f, 0.7275390625f, 0.3896484375f, -0.0439453125f},
};

__device__ __forceinline__ void cubw(int r, int ph, float* w, int& base) {
  base = r + ((ph < 2) ? -2 : -1);
  float sum = 0.f;
#pragma unroll
  for (int i = 0; i < 4; ++i) {
    int idx = base + i;
    float wi = (idx >= 0 && idx < 64) ? c_cubw[ph][i] : 0.f;
    w[i] = wi; sum += wi;
  }
  float inv = 1.f / sum;
#pragma unroll
  for (int i = 0; i < 4; ++i) w[i] *= inv;
}

// ---------------- blend: pixel-shuffle of up + bicubic + mask blend ----------------
__global__ __launch_bounds__(256) void k_blend(
    const bf16* __restrict__ up, const float* __restrict__ x,
    const float* __restrict__ maskp, float* __restrict__ sr) {
  int idx = blockIdx.x * 256 + threadIdx.x;
  int ch = idx >> 20;
  int rem = idx & 1048575;
  int gR = rem >> 10, gC = rem & 1023;
  int th = gR >> 8, tw = gC >> 8;
  int t = th * 4 + tw;
  int R = gR & 255, C = gC & 255;
  int r = R >> 2, a = R & 3, c = C >> 2, b = C & 3;
  float m = maskp[t];
  float outv;
  if (m > 0.5f) {
    int wi = r >> 4, u = r & 15, wj = c >> 4, v = c & 15;
    int wrow = (t * 16 + wi * 4 + wj) * 256 + u * 16 + v;
    outv = bf2f(up[(size_t)wrow * 48 + a * 12 + b * 3 + ch]);
  } else {
    float wy[4], wx[4];
    int yb, xb;
    cubw(r, a, wy, yb);
    cubw(c, b, wx, xb);
    const float* xc = x + ch * 65536;
    float neg = 0.f;
#pragma unroll
    for (int i = 0; i < 4; ++i) {
      int yi = yb + i;
      if (yi < 0 || yi > 63) continue;
      float rowsum = 0.f;
#pragma unroll
      for (int j = 0; j < 4; ++j) {
        int xj = xb + j;
        if (xj < 0 || xj > 63) continue;
        rowsum = fmaf(wx[j], xc[(th * 64 + yi) * 256 + tw * 64 + xj], rowsum);
      }
      neg = fmaf(wy[i], rowsum, neg);
    }
    outv = neg;
  }
  sr[idx] = outv;
}

// ---------------- launcher ----------------
extern "C" void kernel_launch(void* const* d_in, const int* in_sizes, int n_in,
                              void* d_out, int out_size, void* d_ws, size_t ws_size,
                              hipStream_t stream) {
  const float* x     = (const float*)d_in[0];
  const float* gu    = (const float*)d_in[1];
  const float* s1w   = (const float*)d_in[2];
  const float* s1b   = (const float*)d_in[3];
  const float* s2w   = (const float*)d_in[4];
  const float* s2b   = (const float*)d_in[5];
  const float* s3w   = (const float*)d_in[6];
  const float* s3b   = (const float*)d_in[7];
  const float* ew    = (const float*)d_in[8];
  const float* ebias = (const float*)d_in[9];
  const float* ln1g  = (const float*)d_in[10];
  const float* ln1b  = (const float*)d_in[11];
  const float* qkvw  = (const float*)d_in[12];
  const float* qkvb  = (const float*)d_in[13];
  const float* projw = (const float*)d_in[14];
  const float* projb = (const float*)d_in[15];
  const float* ln2g  = (const float*)d_in[16];
  const float* ln2b  = (const float*)d_in[17];
  const float* mlp1w = (const float*)d_in[18];
  const float* mlp1b = (const float*)d_in[19];
  const float* mlp2w = (const float*)d_in[20];
  const float* mlp2b = (const float*)d_in[21];
  const float* upw   = (const float*)d_in[22];
  const float* upb   = (const float*)d_in[23];

  float* out = (float*)d_out;
  float* sr  = out;                 // 3*1024*1024
  float* f3o = out + 3145728;       // 16*2
  float* f2o = f3o + 32;            // 16*32
  float* f1o = f2o + 512;           // 16*64

  char* ws = (char*)d_ws;
  bf16* tok  = (bf16*)(ws);                   // 65536*180 = 23,592,960 B
  bf16* ABuf = (bf16*)(ws + 23592960);        // 65536*192 = 25,165,824 B
  bf16* Qp   = (bf16*)(ws + 48758784);        // 65536*192
  bf16* Kp   = (bf16*)(ws + 73924608);        // 65536*192
  bf16* Vt   = (bf16*)(ws + 99090432);        // 192*65536
  bf16* mid  = Qp;                            // reuse Qp+Kp: 65536*384
  float* maskp   = (float*)(ws + 124256256);  // 64 B
  bf16* Bt_qkv  = (bf16*)(ws + 124256320);    // 576*192*2 = 221,184
  bf16* Bt_proj = (bf16*)(ws + 124477504);    // 192*192*2 = 73,728
  bf16* Bt_mlp1 = (bf16*)(ws + 124551232);    // 384*192*2 = 147,456
  bf16* Bt_mlp2 = (bf16*)(ws + 124698688);    // 192*384*2 = 147,456
  bf16* Bt_up   = (bf16*)(ws + 124846144);    // 64*192*2  = 24,576
  bf16* up      = (bf16*)(ws + 124870720);    // 65536*48*2 = 6,291,456

  k_selector<<<16, 64, 0, stream>>>(x, gu, s1w, s1b, s2w, s2b, s3w, s3b, f1o, f2o, f3o, maskp);
  k_packB<<<1200, 256, 0, stream>>>(qkvw, projw, mlp1w, mlp2w, upw,
                                    Bt_qkv, Bt_proj, Bt_mlp1, Bt_mlp2, Bt_up);
  k_embed<<<16384, 256, 0, stream>>>(x, ew, ebias, ln1g, ln1b, tok, ABuf);
  k_padzero<<<256, 256, 0, stream>>>(Qp, Kp);
  // Q/K/V = LN1(tok) @ qkv_w + qkv_b, split + head-padded
  k_gemm_nloop<192, 128, 3><<<512, 256, 0, stream>>>(
      ABuf, 192, Bt_qkv, qkvb, nullptr, 0, 540, 9, Qp, Kp, Vt);
  k_attn_mfma<<<1536, 256, 0, stream>>>(Qp, Kp, Vt, ABuf);
  // tok += av @ proj_w + proj_b
  k_gemm_nloop<192, 128, 1><<<512, 256, 0, stream>>>(
      ABuf, 192, Bt_proj, projb, tok, 180, 180, 3, nullptr, nullptr, nullptr);
  k_ln2prep<<<16384, 256, 0, stream>>>(tok, ln2g, ln2b, ABuf);
  // mid = gelu(LN2(tok) @ mlp1_w + mlp1_b), zero-padded to 384 cols
  k_gemm_nloop<192, 128, 2><<<512, 256, 0, stream>>>(
      ABuf, 192, Bt_mlp1, mlp1b, mid, 384, 360, 6, nullptr, nullptr, nullptr);
  // tok += mid @ mlp2_w + mlp2_b
  k_gemm_nloop<384, 64, 1><<<1024, 256, 0, stream>>>(
      mid, 384, Bt_mlp2, mlp2b, tok, 180, 180, 3, nullptr, nullptr, nullptr);
  // up = tok @ up_w + up_b
  k_gemm_nloop<192, 128, 0><<<512, 256, 0, stream>>>(
      tok, 180, Bt_up, upb, up, 48, 48, 1, nullptr, nullptr, nullptr);
  k_blend<<<12288, 256, 0, stream>>>(up, x, maskp, sr);
}